// Round 1
// baseline (171.718 us; speedup 1.0000x reference)
//
#include <hip/hip_runtime.h>
#include <math.h>

#define N_G 4096
#define W_IMG 256
#define H_IMG 256

// ---------------- prep: per-gaussian projection ----------------
__global__ __launch_bounds__(256) void prep_kernel(
    const float* __restrict__ pos, const float* __restrict__ scl,
    const float* __restrict__ rot, const float* __restrict__ col,
    const float* __restrict__ opa, const float* __restrict__ vm,
    float* __restrict__ depths, float4* __restrict__ bboxU,
    float4* __restrict__ params)
{
  int i = blockIdx.x * 256 + threadIdx.x;
  if (i >= N_G) return;
  const float FX = 300.f, FY = 300.f, CXc = 128.f, CYc = 128.f;
  float V00=vm[0],V01=vm[1],V02=vm[2],V03=vm[3];
  float V10=vm[4],V11=vm[5],V12=vm[6],V13=vm[7];
  float V20=vm[8],V21=vm[9],V22=vm[10],V23=vm[11];
  float p0=pos[3*i], p1=pos[3*i+1], p2=pos[3*i+2];
  float X = V00*p0+V01*p1+V02*p2+V03;
  float Y = V10*p0+V11*p1+V12*p2+V13;
  float Z = V20*p0+V21*p1+V22*p2+V23;
  float depth = -Z;
  float zp = Z + 1e-8f;
  float sgn = (zp>0.f)?1.f:((zp<0.f)?-1.f:0.f);
  float z_safe = fmaxf(fabsf(Z), 0.01f) * sgn;
  float z2 = z_safe*z_safe;
  // quaternion -> R
  float qw=rot[4*i], qx=rot[4*i+1], qy=rot[4*i+2], qz=rot[4*i+3];
  float qn = sqrtf(qw*qw+qx*qx+qy*qy+qz*qz);
  float qi = 1.f/qn; qw*=qi; qx*=qi; qy*=qi; qz*=qi;
  float R00=1.f-2.f*qy*qy-2.f*qz*qz;
  float R01=2.f*qx*qy-2.f*qw*qz;
  float R02=2.f*qx*qz+2.f*qw*qy;
  float R10=2.f*qx*qy+2.f*qw*qz;
  float R11=1.f-2.f*qx*qx-2.f*qz*qz;
  float R12=2.f*qy*qz-2.f*qw*qx;
  float R20=2.f*qx*qz-2.f*qw*qy;
  float R21=2.f*qy*qz+2.f*qw*qx;
  float R22=1.f-2.f*qx*qx-2.f*qy*qy;
  // R_cam = V[:3,:3] @ R
  float C00=V00*R00+V01*R10+V02*R20;
  float C01=V00*R01+V01*R11+V02*R21;
  float C02=V00*R02+V01*R12+V02*R22;
  float C10=V10*R00+V11*R10+V12*R20;
  float C11=V10*R01+V11*R11+V12*R21;
  float C12=V10*R02+V11*R12+V12*R22;
  float C20=V20*R00+V21*R10+V22*R20;
  float C21=V20*R01+V21*R11+V22*R21;
  float C22=V20*R02+V21*R12+V22*R22;
  float s0=scl[3*i], s1=scl[3*i+1], s2=scl[3*i+2];
  float S00=C00*s0,S01=C01*s1,S02=C02*s2;
  float S10=C10*s0,S11=C11*s1,S12=C12*s2;
  float S20=C20*s0,S21=C21*s1,S22=C22*s2;
  // cov3d = RS @ RS^T (symmetric)
  float c00=S00*S00+S01*S01+S02*S02;
  float c01=S00*S10+S01*S11+S02*S12;
  float c02=S00*S20+S01*S21+S02*S22;
  float c11=S10*S10+S11*S11+S12*S12;
  float c12=S10*S20+S11*S21+S12*S22;
  float c22=S20*S20+S21*S21+S22*S22;
  float j00=FX/(-z_safe), j02=FX*X/z2;
  float j11=FY/z_safe,    j12=FY*Y/z2;
  // M = J @ cov3d (2x3)
  float M00=j00*c00+j02*c02;
  float M01=j00*c01+j02*c12;
  float M02=j00*c02+j02*c22;
  float M10=j11*c01+j12*c02;
  float M11=j11*c11+j12*c12;
  float M12=j11*c12+j12*c22;
  // cov2d = M @ J^T
  float a =M00*j00+M02*j02;
  float b =M01*j11+M02*j12;
  float c_=M10*j00+M12*j02;
  float d =M11*j11+M12*j12;
  float u = FX*X/(-z_safe)+CXc;
  float v = FY*(-Y)/(-z_safe)+CYc;
  float tr=a+d;
  float det=fmaxf(a*d-b*c_, 1e-6f);
  float disc=fmaxf(tr*tr-4.f*det, 0.f);
  float lam=(tr+sqrtf(disc))*0.5f;
  float radius=fminf(3.f*sqrtf(fmaxf(lam,1e-6f)), 64.f);
  bool vis = (depth>0.01f)&&(depth<100.f)
          && (u+radius>0.f)&&(u-radius<(float)W_IMG)
          && (v+radius>0.f)&&(v-radius<(float)H_IMG);
  float o = vis ? opa[i] : 0.f;
  float ar=a+1e-4f, dr=d+1e-4f;
  float inv_det=1.f/(ar*dr-b*c_);
  float ia=dr*inv_det, ib=-b*inv_det, ic=-c_*inv_det, idd=ar*inv_det;
  float Lx,Ux,Ly,Uy;
  if (o>0.f) {
    Lx=truncf(u-radius); Ux=truncf(u+radius);
    Ly=truncf(v-radius); Uy=truncf(v+radius);
  } else {
    Lx=1e9f; Ux=-1e9f; Ly=1e9f; Uy=-1e9f;  // never intersects any tile
  }
  depths[i]=depth;
  bboxU[i]=make_float4(Lx,Ux,Ly,Uy);
  params[3*i+0]=make_float4(u,v,ia,ib+ic);
  params[3*i+1]=make_float4(idd,o,col[3*i],col[3*i+1]);
  params[3*i+2]=make_float4(col[3*i+2],0.f,0.f,0.f);
}

// ------------- rank: stable O(N^2) depth sort + scatter -------------
__global__ __launch_bounds__(256) void rank_kernel(
    const float* __restrict__ depths, const float4* __restrict__ bboxU,
    float4* __restrict__ bboxS, int* __restrict__ idxS)
{
  __shared__ float4 sd[N_G/4];
  int tid = threadIdx.x;
  const float4* d4 = (const float4*)depths;
  for (int k=tid; k<N_G/4; k+=256) sd[k]=d4[k];
  __syncthreads();
  int i = blockIdx.x*256 + tid;
  float di = depths[i];
  int r = 0;
  #pragma unroll 8
  for (int k=0; k<N_G/4; k++) {
    float4 v = sd[k];
    int j = 4*k;
    r += (v.x<di) || ((v.x==di)&&(j  <i));
    r += (v.y<di) || ((v.y==di)&&(j+1<i));
    r += (v.z<di) || ((v.z==di)&&(j+2<i));
    r += (v.w<di) || ((v.w==di)&&(j+3<i));
  }
  bboxS[r] = bboxU[i];  // depth-sorted bboxes: coalesced scan in render
  idxS[r] = i;
}

// ------------- render: one wave per 8x8 tile -------------
__global__ __launch_bounds__(64) void render_kernel(
    const float4* __restrict__ bboxS, const int* __restrict__ idxS,
    const float4* __restrict__ params, float* __restrict__ out)
{
  __shared__ float4 sgA[64], sgB[64], sgC[64], sgD[64];
  int tid = threadIdx.x;                    // block == one wave64
  int tX = blockIdx.x & 31, tY = blockIdx.x >> 5;
  float X0=(float)(tX*8), Y0=(float)(tY*8);
  float X1=X0+7.f, Y1=Y0+7.f;
  float px=X0+(float)(tid&7), py=Y0+(float)(tid>>3);
  float aR=0.f,aG=0.f,aB=0.f,aA=0.f;
  for (int base=0; base<N_G; base+=64) {
    float4 bb = bboxS[base+tid];
    bool pred = (bb.y>=X0)&&(bb.x<=X1)&&(bb.w>=Y0)&&(bb.z<=Y1);
    unsigned long long mask = __ballot(pred);
    int total = __popcll(mask);             // wave-uniform
    if (total==0) continue;
    if (pred) {
      int posn = __popcll(mask & ((1ull<<tid)-1ull));  // stable order
      int idx = idxS[base+tid];
      float4 p0=params[3*idx], p1=params[3*idx+1], p2=params[3*idx+2];
      sgA[posn]=p0;
      sgB[posn]=p1;
      sgC[posn]=make_float4(p2.x, bb.x, bb.y, bb.z);
      sgD[posn]=make_float4(bb.w, 0.f, 0.f, 0.f);
    }
    __syncthreads();
    for (int k=0; k<total; k++) {
      float4 gA=sgA[k], gB=sgB[k], gC=sgC[k], gD=sgD[k];
      float dx=px-gA.x, dy=py-gA.y;
      float power = -0.5f*(gA.z*dx*dx + gA.w*dx*dy + gB.x*dy*dy);
      bool inside = (px>=gC.y)&&(px<=gC.z)&&(py>=gC.w)&&(py<=gD.x);
      float alpha = inside ? gB.y*__expf(power) : 0.f;
      float w = alpha*(1.f-aA);
      aR += w*gB.z; aG += w*gB.w; aB += w*gC.x; aA += w;
    }
    __syncthreads();
    if (__ballot(aA<=0.9999f)==0ull) break;   // residual < 1e-4 << threshold
  }
  int x=tX*8+(tid&7), y=tY*8+(tid>>3);
  out[0*H_IMG*W_IMG + y*W_IMG + x]=aR;
  out[1*H_IMG*W_IMG + y*W_IMG + x]=aG;
  out[2*H_IMG*W_IMG + y*W_IMG + x]=aB;
}

extern "C" void kernel_launch(void* const* d_in, const int* in_sizes, int n_in,
                              void* d_out, int out_size, void* d_ws, size_t ws_size,
                              hipStream_t stream)
{
  const float* pos=(const float*)d_in[0];
  const float* scl=(const float*)d_in[1];
  const float* rot=(const float*)d_in[2];
  const float* col=(const float*)d_in[3];
  const float* opa=(const float*)d_in[4];
  const float* vm =(const float*)d_in[5];
  float* out=(float*)d_out;
  char* ws=(char*)d_ws;
  // layout: depths 16K | bboxU 64K | params 192K | bboxS 64K | idxS 16K = 352KB
  float*  depths=(float*) (ws);
  float4* bboxU =(float4*)(ws + 16*1024);
  float4* params=(float4*)(ws + 80*1024);
  float4* bboxS =(float4*)(ws + 272*1024);
  int*    idxS  =(int*)   (ws + 336*1024);
  prep_kernel<<<N_G/256, 256, 0, stream>>>(pos,scl,rot,col,opa,vm,depths,bboxU,params);
  rank_kernel<<<N_G/256, 256, 0, stream>>>(depths,bboxU,bboxS,idxS);
  render_kernel<<<1024, 64, 0, stream>>>(bboxS,idxS,params,out);
}

// Round 2
// 61.269 us; speedup vs baseline: 2.8027x; 2.8027x over previous
//
#include <hip/hip_runtime.h>
#include <math.h>

#define N_G 4096
#define W_IMG 256
#define H_IMG 256

// ---------------- prep: per-gaussian projection ----------------
__global__ __launch_bounds__(256) void prep_kernel(
    const float* __restrict__ pos, const float* __restrict__ scl,
    const float* __restrict__ rot, const float* __restrict__ col,
    const float* __restrict__ opa, const float* __restrict__ vm,
    float* __restrict__ depths, float4* __restrict__ bboxU,
    float4* __restrict__ params, int* __restrict__ rank)
{
  int i = blockIdx.x * 256 + threadIdx.x;
  if (i >= N_G) return;
  rank[i] = 0;                               // zero for rank_partial atomics
  const float FX = 300.f, FY = 300.f, CXc = 128.f, CYc = 128.f;
  float V00=vm[0],V01=vm[1],V02=vm[2],V03=vm[3];
  float V10=vm[4],V11=vm[5],V12=vm[6],V13=vm[7];
  float V20=vm[8],V21=vm[9],V22=vm[10],V23=vm[11];
  float p0=pos[3*i], p1=pos[3*i+1], p2=pos[3*i+2];
  float X = V00*p0+V01*p1+V02*p2+V03;
  float Y = V10*p0+V11*p1+V12*p2+V13;
  float Z = V20*p0+V21*p1+V22*p2+V23;
  float depth = -Z;
  float zp = Z + 1e-8f;
  float sgn = (zp>0.f)?1.f:((zp<0.f)?-1.f:0.f);
  float z_safe = fmaxf(fabsf(Z), 0.01f) * sgn;
  float z2 = z_safe*z_safe;
  // quaternion -> R
  float qw=rot[4*i], qx=rot[4*i+1], qy=rot[4*i+2], qz=rot[4*i+3];
  float qn = sqrtf(qw*qw+qx*qx+qy*qy+qz*qz);
  float qi = 1.f/qn; qw*=qi; qx*=qi; qy*=qi; qz*=qi;
  float R00=1.f-2.f*qy*qy-2.f*qz*qz;
  float R01=2.f*qx*qy-2.f*qw*qz;
  float R02=2.f*qx*qz+2.f*qw*qy;
  float R10=2.f*qx*qy+2.f*qw*qz;
  float R11=1.f-2.f*qx*qx-2.f*qz*qz;
  float R12=2.f*qy*qz-2.f*qw*qx;
  float R20=2.f*qx*qz-2.f*qw*qy;
  float R21=2.f*qy*qz+2.f*qw*qx;
  float R22=1.f-2.f*qx*qx-2.f*qy*qy;
  // R_cam = V[:3,:3] @ R
  float C00=V00*R00+V01*R10+V02*R20;
  float C01=V00*R01+V01*R11+V02*R21;
  float C02=V00*R02+V01*R12+V02*R22;
  float C10=V10*R00+V11*R10+V12*R20;
  float C11=V10*R01+V11*R11+V12*R21;
  float C12=V10*R02+V11*R12+V12*R22;
  float C20=V20*R00+V21*R10+V22*R20;
  float C21=V20*R01+V21*R11+V22*R21;
  float C22=V20*R02+V21*R12+V22*R22;
  float s0=scl[3*i], s1=scl[3*i+1], s2=scl[3*i+2];
  float S00=C00*s0,S01=C01*s1,S02=C02*s2;
  float S10=C10*s0,S11=C11*s1,S12=C12*s2;
  float S20=C20*s0,S21=C21*s1,S22=C22*s2;
  // cov3d = RS @ RS^T (symmetric)
  float c00=S00*S00+S01*S01+S02*S02;
  float c01=S00*S10+S01*S11+S02*S12;
  float c02=S00*S20+S01*S21+S02*S22;
  float c11=S10*S10+S11*S11+S12*S12;
  float c12=S10*S20+S11*S21+S12*S22;
  float c22=S20*S20+S21*S21+S22*S22;
  float j00=FX/(-z_safe), j02=FX*X/z2;
  float j11=FY/z_safe,    j12=FY*Y/z2;
  // M = J @ cov3d (2x3)
  float M00=j00*c00+j02*c02;
  float M01=j00*c01+j02*c12;
  float M02=j00*c02+j02*c22;
  float M10=j11*c01+j12*c02;
  float M11=j11*c11+j12*c12;
  float M12=j11*c12+j12*c22;
  // cov2d = M @ J^T
  float a =M00*j00+M02*j02;
  float b =M01*j11+M02*j12;
  float c_=M10*j00+M12*j02;
  float d =M11*j11+M12*j12;
  float u = FX*X/(-z_safe)+CXc;
  float v = FY*(-Y)/(-z_safe)+CYc;
  float tr=a+d;
  float det=fmaxf(a*d-b*c_, 1e-6f);
  float disc=fmaxf(tr*tr-4.f*det, 0.f);
  float lam=(tr+sqrtf(disc))*0.5f;
  float radius=fminf(3.f*sqrtf(fmaxf(lam,1e-6f)), 64.f);
  bool vis = (depth>0.01f)&&(depth<100.f)
          && (u+radius>0.f)&&(u-radius<(float)W_IMG)
          && (v+radius>0.f)&&(v-radius<(float)H_IMG);
  float o = vis ? opa[i] : 0.f;
  float ar=a+1e-4f, dr=d+1e-4f;
  float inv_det=1.f/(ar*dr-b*c_);
  float ia=dr*inv_det, ib=-b*inv_det, ic=-c_*inv_det, idd=ar*inv_det;
  float Lx,Ux,Ly,Uy;
  if (o>0.f) {
    Lx=truncf(u-radius); Ux=truncf(u+radius);
    Ly=truncf(v-radius); Uy=truncf(v+radius);
  } else {
    Lx=1e9f; Ux=-1e9f; Ly=1e9f; Uy=-1e9f;  // never intersects any tile
  }
  depths[i]=depth;
  bboxU[i]=make_float4(Lx,Ux,Ly,Uy);
  params[3*i+0]=make_float4(u,v,ia,ib+ic);
  params[3*i+1]=make_float4(idd,o,col[3*i],col[3*i+1]);
  params[3*i+2]=make_float4(col[3*i+2],0.f,0.f,0.f);
}

// ------- rank_partial: 2D-decomposed stable rank (256 blocks) -------
// block (bi,bk): ranks of i in bi-chunk counted against k in bk-chunk.
__global__ __launch_bounds__(256) void rank_partial(
    const float* __restrict__ depths, int* __restrict__ rank)
{
  __shared__ float4 sd[64];
  int tid = threadIdx.x;
  int bi = blockIdx.x, bk = blockIdx.y;
  if (tid < 64) sd[tid] = ((const float4*)depths)[bk*64 + tid];
  __syncthreads();
  int i = bi*256 + tid;
  float di = depths[i];
  int kbase = bk*256;
  int r = 0;
  #pragma unroll 16
  for (int k=0; k<64; k++) {
    float4 v = sd[k];
    int j = kbase + 4*k;
    r += (v.x<di) || ((v.x==di)&&(j  <i));
    r += (v.y<di) || ((v.y==di)&&(j+1<i));
    r += (v.z<di) || ((v.z==di)&&(j+2<i));
    r += (v.w<di) || ((v.w==di)&&(j+3<i));
  }
  atomicAdd(&rank[i], r);   // int add: commutative -> deterministic
}

// ------- scatter: permute bbox/idx into depth-sorted order -------
__global__ __launch_bounds__(256) void scatter_kernel(
    const int* __restrict__ rank, const float4* __restrict__ bboxU,
    float4* __restrict__ bboxS, int* __restrict__ idxS)
{
  int i = blockIdx.x*256 + threadIdx.x;
  int r = rank[i];
  bboxS[r] = bboxU[i];
  idxS[r] = i;
}

// ------------- render: one wave per 8x8 tile -------------
__global__ __launch_bounds__(64) void render_kernel(
    const float4* __restrict__ bboxS, const int* __restrict__ idxS,
    const float4* __restrict__ params, float* __restrict__ out)
{
  __shared__ float4 sgA[64], sgB[64], sgC[64], sgD[64];
  int tid = threadIdx.x;                    // block == one wave64
  int tX = blockIdx.x & 31, tY = blockIdx.x >> 5;
  float X0=(float)(tX*8), Y0=(float)(tY*8);
  float X1=X0+7.f, Y1=Y0+7.f;
  float px=X0+(float)(tid&7), py=Y0+(float)(tid>>3);
  float aR=0.f,aG=0.f,aB=0.f,aA=0.f;
  for (int base=0; base<N_G; base+=64) {
    float4 bb = bboxS[base+tid];
    bool pred = (bb.y>=X0)&&(bb.x<=X1)&&(bb.w>=Y0)&&(bb.z<=Y1);
    unsigned long long mask = __ballot(pred);
    int total = __popcll(mask);             // wave-uniform
    if (total==0) continue;
    if (pred) {
      int posn = __popcll(mask & ((1ull<<tid)-1ull));  // stable order
      int idx = idxS[base+tid];
      float4 p0=params[3*idx], p1=params[3*idx+1], p2=params[3*idx+2];
      sgA[posn]=p0;
      sgB[posn]=p1;
      sgC[posn]=make_float4(p2.x, bb.x, bb.y, bb.z);
      sgD[posn]=make_float4(bb.w, 0.f, 0.f, 0.f);
    }
    __syncthreads();
    for (int k=0; k<total; k++) {
      float4 gA=sgA[k], gB=sgB[k], gC=sgC[k], gD=sgD[k];
      float dx=px-gA.x, dy=py-gA.y;
      float power = -0.5f*(gA.z*dx*dx + gA.w*dx*dy + gB.x*dy*dy);
      bool inside = (px>=gC.y)&&(px<=gC.z)&&(py>=gC.w)&&(py<=gD.x);
      float alpha = inside ? gB.y*__expf(power) : 0.f;
      float w = alpha*(1.f-aA);
      aR += w*gB.z; aG += w*gB.w; aB += w*gC.x; aA += w;
    }
    __syncthreads();
    if (__ballot(aA<=0.9999f)==0ull) break;   // residual < 1e-4 << threshold
  }
  int x=tX*8+(tid&7), y=tY*8+(tid>>3);
  out[0*H_IMG*W_IMG + y*W_IMG + x]=aR;
  out[1*H_IMG*W_IMG + y*W_IMG + x]=aG;
  out[2*H_IMG*W_IMG + y*W_IMG + x]=aB;
}

extern "C" void kernel_launch(void* const* d_in, const int* in_sizes, int n_in,
                              void* d_out, int out_size, void* d_ws, size_t ws_size,
                              hipStream_t stream)
{
  const float* pos=(const float*)d_in[0];
  const float* scl=(const float*)d_in[1];
  const float* rot=(const float*)d_in[2];
  const float* col=(const float*)d_in[3];
  const float* opa=(const float*)d_in[4];
  const float* vm =(const float*)d_in[5];
  float* out=(float*)d_out;
  char* ws=(char*)d_ws;
  // layout: depths 16K | bboxU 64K | params 192K | bboxS 64K | idxS 16K | rank 16K
  float*  depths=(float*) (ws);
  float4* bboxU =(float4*)(ws + 16*1024);
  float4* params=(float4*)(ws + 80*1024);
  float4* bboxS =(float4*)(ws + 272*1024);
  int*    idxS  =(int*)   (ws + 336*1024);
  int*    rank  =(int*)   (ws + 352*1024);
  prep_kernel<<<N_G/256, 256, 0, stream>>>(pos,scl,rot,col,opa,vm,depths,bboxU,params,rank);
  dim3 rg(N_G/256, N_G/256);
  rank_partial<<<rg, 256, 0, stream>>>(depths, rank);
  scatter_kernel<<<N_G/256, 256, 0, stream>>>(rank, bboxU, bboxS, idxS);
  render_kernel<<<1024, 64, 0, stream>>>(bboxS,idxS,params,out);
}

// Round 3
// 46.611 us; speedup vs baseline: 3.6840x; 1.3145x over previous
//
#include <hip/hip_runtime.h>
#include <math.h>

#define N_G 4096
#define W_IMG 256
#define H_IMG 256
#define N_TILE 1024      // 32x32 tiles of 8x8 px
#define N_CHUNK 64       // 4096/64

// ---------------- prep: per-gaussian projection ----------------
__global__ __launch_bounds__(256) void prep_kernel(
    const float* __restrict__ pos, const float* __restrict__ scl,
    const float* __restrict__ rot, const float* __restrict__ col,
    const float* __restrict__ opa, const float* __restrict__ vm,
    float* __restrict__ depths, float4* __restrict__ bboxU,
    float4* __restrict__ params, int* __restrict__ rank)
{
  int i = blockIdx.x * 256 + threadIdx.x;
  if (i >= N_G) return;
  rank[i] = 0;                               // zero for rank_partial atomics
  const float FX = 300.f, FY = 300.f, CXc = 128.f, CYc = 128.f;
  float V00=vm[0],V01=vm[1],V02=vm[2],V03=vm[3];
  float V10=vm[4],V11=vm[5],V12=vm[6],V13=vm[7];
  float V20=vm[8],V21=vm[9],V22=vm[10],V23=vm[11];
  float p0=pos[3*i], p1=pos[3*i+1], p2=pos[3*i+2];
  float X = V00*p0+V01*p1+V02*p2+V03;
  float Y = V10*p0+V11*p1+V12*p2+V13;
  float Z = V20*p0+V21*p1+V22*p2+V23;
  float depth = -Z;
  float zp = Z + 1e-8f;
  float sgn = (zp>0.f)?1.f:((zp<0.f)?-1.f:0.f);
  float z_safe = fmaxf(fabsf(Z), 0.01f) * sgn;
  float z2 = z_safe*z_safe;
  float qw=rot[4*i], qx=rot[4*i+1], qy=rot[4*i+2], qz=rot[4*i+3];
  float qn = sqrtf(qw*qw+qx*qx+qy*qy+qz*qz);
  float qi = 1.f/qn; qw*=qi; qx*=qi; qy*=qi; qz*=qi;
  float R00=1.f-2.f*qy*qy-2.f*qz*qz;
  float R01=2.f*qx*qy-2.f*qw*qz;
  float R02=2.f*qx*qz+2.f*qw*qy;
  float R10=2.f*qx*qy+2.f*qw*qz;
  float R11=1.f-2.f*qx*qx-2.f*qz*qz;
  float R12=2.f*qy*qz-2.f*qw*qx;
  float R20=2.f*qx*qz-2.f*qw*qy;
  float R21=2.f*qy*qz+2.f*qw*qx;
  float R22=1.f-2.f*qx*qx-2.f*qy*qy;
  float C00=V00*R00+V01*R10+V02*R20;
  float C01=V00*R01+V01*R11+V02*R21;
  float C02=V00*R02+V01*R12+V02*R22;
  float C10=V10*R00+V11*R10+V12*R20;
  float C11=V10*R01+V11*R11+V12*R21;
  float C12=V10*R02+V11*R12+V12*R22;
  float C20=V20*R00+V21*R10+V22*R20;
  float C21=V20*R01+V21*R11+V22*R21;
  float C22=V20*R02+V21*R12+V22*R22;
  float s0=scl[3*i], s1=scl[3*i+1], s2=scl[3*i+2];
  float S00=C00*s0,S01=C01*s1,S02=C02*s2;
  float S10=C10*s0,S11=C11*s1,S12=C12*s2;
  float S20=C20*s0,S21=C21*s1,S22=C22*s2;
  float c00=S00*S00+S01*S01+S02*S02;
  float c01=S00*S10+S01*S11+S02*S12;
  float c02=S00*S20+S01*S21+S02*S22;
  float c11=S10*S10+S11*S11+S12*S12;
  float c12=S10*S20+S11*S21+S12*S22;
  float c22=S20*S20+S21*S21+S22*S22;
  float j00=FX/(-z_safe), j02=FX*X/z2;
  float j11=FY/z_safe,    j12=FY*Y/z2;
  float M00=j00*c00+j02*c02;
  float M01=j00*c01+j02*c12;
  float M02=j00*c02+j02*c22;
  float M10=j11*c01+j12*c02;
  float M11=j11*c11+j12*c12;
  float M12=j11*c12+j12*c22;
  float a =M00*j00+M02*j02;
  float b =M01*j11+M02*j12;
  float c_=M10*j00+M12*j02;
  float d =M11*j11+M12*j12;
  float u = FX*X/(-z_safe)+CXc;
  float v = FY*(-Y)/(-z_safe)+CYc;
  float tr=a+d;
  float det=fmaxf(a*d-b*c_, 1e-6f);
  float disc=fmaxf(tr*tr-4.f*det, 0.f);
  float lam=(tr+sqrtf(disc))*0.5f;
  float radius=fminf(3.f*sqrtf(fmaxf(lam,1e-6f)), 64.f);
  bool vis = (depth>0.01f)&&(depth<100.f)
          && (u+radius>0.f)&&(u-radius<(float)W_IMG)
          && (v+radius>0.f)&&(v-radius<(float)H_IMG);
  float o = vis ? opa[i] : 0.f;
  float ar=a+1e-4f, dr=d+1e-4f;
  float inv_det=1.f/(ar*dr-b*c_);
  float ia=dr*inv_det, ib=-b*inv_det, ic=-c_*inv_det, idd=ar*inv_det;
  float Lx,Ux,Ly,Uy;
  if (o>0.f) {
    Lx=truncf(u-radius); Ux=truncf(u+radius);
    Ly=truncf(v-radius); Uy=truncf(v+radius);
  } else {
    Lx=1e9f; Ux=-1e9f; Ly=1e9f; Uy=-1e9f;  // never intersects any tile
  }
  depths[i]=depth;
  bboxU[i]=make_float4(Lx,Ux,Ly,Uy);
  params[3*i+0]=make_float4(u,v,ia,ib+ic);
  params[3*i+1]=make_float4(idd,o,col[3*i],col[3*i+1]);
  params[3*i+2]=make_float4(col[3*i+2],0.f,0.f,0.f);
}

// ------- rank_partial: 2D-decomposed stable rank -------
__global__ __launch_bounds__(256) void rank_partial(
    const float* __restrict__ depths, int* __restrict__ rank)
{
  __shared__ float4 sd[64];
  int tid = threadIdx.x;
  int bi = blockIdx.x, bk = blockIdx.y;
  if (tid < 64) sd[tid] = ((const float4*)depths)[bk*64 + tid];
  __syncthreads();
  int i = bi*256 + tid;
  float di = depths[i];
  int kbase = bk*256;
  int r = 0;
  #pragma unroll 16
  for (int k=0; k<64; k++) {
    float4 v = sd[k];
    int j = kbase + 4*k;
    r += (v.x<di) || ((v.x==di)&&(j  <i));
    r += (v.y<di) || ((v.y==di)&&(j+1<i));
    r += (v.z<di) || ((v.z==di)&&(j+2<i));
    r += (v.w<di) || ((v.w==di)&&(j+3<i));
  }
  atomicAdd(&rank[i], r);   // int add: commutative -> deterministic
}

// ------- scatter: pack sorted-order per-gaussian struct + bbox -------
__global__ __launch_bounds__(256) void scatter_kernel(
    const int* __restrict__ rank, const float4* __restrict__ bboxU,
    const float4* __restrict__ params,
    float4* __restrict__ bboxS, float4* __restrict__ gaussS)
{
  int i = blockIdx.x*256 + threadIdx.x;
  int r = rank[i];
  float4 bb = bboxU[i];
  float4 p0 = params[3*i], p1 = params[3*i+1], p2 = params[3*i+2];
  bboxS[r] = bb;
  gaussS[4*r+0] = p0;                                   // u,v,ia,ib+ic
  gaussS[4*r+1] = p1;                                   // idd,o,colR,colG
  gaussS[4*r+2] = make_float4(p2.x, bb.x, bb.y, bb.z);  // colB,Lx,Ux,Ly
  gaussS[4*r+3] = make_float4(bb.w, 0.f, 0.f, 0.f);     // Uy
}

// ------- mask: per (tile, chunk) 64-bit intersect mask -------
__global__ __launch_bounds__(64) void mask_kernel(
    const float4* __restrict__ bboxS, unsigned long long* __restrict__ masks)
{
  int tid = threadIdx.x;
  int tile = blockIdx.x, q = blockIdx.y;
  int tX = tile & 31, tY = tile >> 5;
  float X0=(float)(tX*8), Y0=(float)(tY*8);
  float X1=X0+7.f, Y1=Y0+7.f;
  #pragma unroll
  for (int c=0; c<16; c++) {
    int chunk = q*16 + c;
    float4 bb = bboxS[chunk*64 + tid];
    bool pred = (bb.y>=X0)&&(bb.x<=X1)&&(bb.w>=Y0)&&(bb.z<=Y1);
    unsigned long long m = __ballot(pred);
    if (tid==0) masks[tile*N_CHUNK + chunk] = m;
  }
}

// ------- fill: wave-scan chunk offsets, scatter sorted ids to tile lists ---
__global__ __launch_bounds__(64) void fill_kernel(
    const unsigned long long* __restrict__ masks,
    int* __restrict__ tileList, int* __restrict__ tileLen, int CAP)
{
  int lane = threadIdx.x;
  int tile = blockIdx.x, q = blockIdx.y;
  unsigned long long mAll = masks[tile*N_CHUNK + lane];  // lane = chunk id
  int c = __popcll(mAll);
  int x = c;
  #pragma unroll
  for (int d=1; d<64; d<<=1) { int y=__shfl_up(x,d); if (lane>=d) x+=y; }
  int offExc = x - c;            // exclusive prefix of chunk counts
  if (q==0 && lane==63) tileLen[tile] = (x<CAP)?x:CAP;
  #pragma unroll
  for (int c16=0; c16<16; c16++) {
    int chunk = q*16 + c16;
    unsigned long long m = __shfl(mAll, chunk);
    int off = __shfl(offExc, chunk);
    if (m & (1ull<<lane)) {
      int posn = off + __popcll(m & ((1ull<<lane)-1ull));
      if (posn < CAP) tileList[tile*CAP + posn] = chunk*64 + lane;
    }
  }
}

// ------------- render: one wave per 8x8 tile, dense sorted list -------------
__global__ __launch_bounds__(64) void render_kernel(
    const int* __restrict__ tileList, const int* __restrict__ tileLen,
    const float4* __restrict__ gaussS, float* __restrict__ out, int CAP)
{
  __shared__ float4 sgA[64], sgB[64], sgC[64], sgD[64];
  int tid = threadIdx.x;                    // block == one wave64
  int tile = blockIdx.x;
  int tX = tile & 31, tY = tile >> 5;
  float px=(float)(tX*8+(tid&7)), py=(float)(tY*8+(tid>>3));
  float aR=0.f,aG=0.f,aB=0.f,aA=0.f;
  int len = tileLen[tile];
  for (int base=0; base<len; base+=64) {
    int rem = len - base;
    int total = rem<64?rem:64;
    if (tid < total) {
      int sp = tileList[tile*CAP + base + tid];
      const float4* g = &gaussS[4*sp];
      sgA[tid]=g[0]; sgB[tid]=g[1]; sgC[tid]=g[2]; sgD[tid]=g[3];
    }
    __syncthreads();
    float4 A=sgA[0],B=sgB[0],C=sgC[0],D=sgD[0];
    for (int k=0; k<total; k++) {
      int kn = (k+1<total)?(k+1):k;
      float4 An=sgA[kn],Bn=sgB[kn],Cn=sgC[kn],Dn=sgD[kn];  // prefetch
      float dx=px-A.x, dy=py-A.y;
      float power = -0.5f*(A.z*dx*dx + A.w*dx*dy + B.x*dy*dy);
      bool inside = (px>=C.y)&&(px<=C.z)&&(py>=C.w)&&(py<=D.x);
      float alpha = inside ? B.y*__expf(power) : 0.f;
      float w = alpha*(1.f-aA);
      aR += w*B.z; aG += w*B.w; aB += w*C.x; aA += w;
      A=An;B=Bn;C=Cn;D=Dn;
    }
    __syncthreads();
    if (__ballot(aA<=0.9999f)==0ull) break;   // residual < 1e-4 << threshold
  }
  int x=tX*8+(tid&7), y=tY*8+(tid>>3);
  out[0*H_IMG*W_IMG + y*W_IMG + x]=aR;
  out[1*H_IMG*W_IMG + y*W_IMG + x]=aG;
  out[2*H_IMG*W_IMG + y*W_IMG + x]=aB;
}

extern "C" void kernel_launch(void* const* d_in, const int* in_sizes, int n_in,
                              void* d_out, int out_size, void* d_ws, size_t ws_size,
                              hipStream_t stream)
{
  const float* pos=(const float*)d_in[0];
  const float* scl=(const float*)d_in[1];
  const float* rot=(const float*)d_in[2];
  const float* col=(const float*)d_in[3];
  const float* opa=(const float*)d_in[4];
  const float* vm =(const float*)d_in[5];
  float* out=(float*)d_out;
  char* ws=(char*)d_ws;
  // ws layout (KB): depths 0-16 | bboxU 16-80 | params 80-272 | rank 272-288
  //                 bboxS 288-352 | gaussS 352-608 | masks 608-1120
  //                 tileLen 1120-1124 | tileList 1124-...
  float*  depths=(float*) (ws);
  float4* bboxU =(float4*)(ws + 16*1024);
  float4* params=(float4*)(ws + 80*1024);
  int*    rank  =(int*)   (ws + 272*1024);
  float4* bboxS =(float4*)(ws + 288*1024);
  float4* gaussS=(float4*)(ws + 352*1024);
  unsigned long long* masks=(unsigned long long*)(ws + 608*1024);
  int*    tileLen=(int*)  (ws + 1120*1024);
  int*    tileList=(int*) (ws + 1124*1024);
  size_t fixed = 1124*1024;
  int CAP = 1024;
  if (ws_size < fixed + (size_t)CAP*N_TILE*4) {
    size_t avail = (ws_size > fixed) ? (ws_size - fixed)/(N_TILE*4) : 64;
    CAP = (int)((avail < 1024) ? avail : 1024);
    if (CAP < 64) CAP = 64;
  }
  prep_kernel<<<N_G/256, 256, 0, stream>>>(pos,scl,rot,col,opa,vm,depths,bboxU,params,rank);
  dim3 rg(N_G/256, N_G/256);
  rank_partial<<<rg, 256, 0, stream>>>(depths, rank);
  scatter_kernel<<<N_G/256, 256, 0, stream>>>(rank, bboxU, params, bboxS, gaussS);
  dim3 mg(N_TILE, 4);
  mask_kernel<<<mg, 64, 0, stream>>>(bboxS, masks);
  fill_kernel<<<mg, 64, 0, stream>>>(masks, tileList, tileLen, CAP);
  render_kernel<<<N_TILE, 64, 0, stream>>>(tileList, tileLen, gaussS, out, CAP);
}